// Round 1
// baseline (271.625 us; speedup 1.0000x reference)
//
#include <hip/hip_runtime.h>
#include <stdint.h>

#define B_      16
#define F_      257
#define T_      8000
#define NB_     64
#define TT_     64
#define NTILES  125
#define TPC     4      // body tiles per chunk
#define NCHUNK  32
#define WTILES  3      // warm-up tiles (192 steps; contraction 0.9526^192 ~ 9e-5)

typedef __attribute__((ext_vector_type(8))) short short8;
typedef __attribute__((ext_vector_type(4))) float floatx4;

__device__ __forceinline__ unsigned short f2bf(float x) {
    union { float f; unsigned u; } v; v.f = x;
    unsigned r = v.u + 0x7FFFu + ((v.u >> 16) & 1u);   // RNE
    return (unsigned short)(r >> 16);
}
__device__ __forceinline__ float bf2f(unsigned short h) {
    union { float f; unsigned u; } v; v.u = ((unsigned)h) << 16;
    return v.f;
}

// LDS tile: conceptual bf16 [t in 0..63][f in 0..255], physical uint16 index:
//   idx16(t,f) = t*256 + (f ^ ((t&15)<<3))
// - swizzle is at 8-element (16B) granularity -> b128 frag loads stay contiguous+aligned
// - scan access (fixed t, lanes=f contiguous): conflict-free
// - einsum B-frag b128 (lanes vary t): ~4-way worst, acceptable

__global__ __launch_bounds__(256, 2) void vnr_fused_kernel(
    const float* __restrict__ mag, const float* __restrict__ fb,
    const float* __restrict__ p_ns, const float* __restrict__ p_rr,
    const float* __restrict__ p_rf, float* __restrict__ out)
{
    __shared__ unsigned short tile16[64 * 256];   // 32 KB
    __shared__ float mag256s[64];
    __shared__ float vnr256s[64];

    const int tid  = threadIdx.x;
    const int lane = tid & 63;
    const int w    = tid >> 6;          // wave 0..3
    const int l15  = tid & 15;
    const int q    = (tid & 63) >> 4;   // quad in wave

    const int bid = blockIdx.x;
    const int b   = bid & 15;
    const int c   = bid >> 4;           // chunk 0..31

    const float ns   = fabsf(p_ns[0]);
    const float rise = 1.0f / (1.0f + __expf(-p_rr[0]));
    const float fall = 1.0f / (1.0f + __expf(-p_rf[0]));

    const float* magp = mag + (size_t)b * (size_t)F_ * (size_t)T_;

    // ---- A-operand fragments (fb) straight into VGPRs, bf16-packed ----
    // lane holds A[m = 16w + l15][f = 32*kt + 8q + j], j=0..7
    short8 afrag[8];
    {
        const float* fbrow = fb + (16 * w + l15) * F_;
        #pragma unroll
        for (int kt = 0; kt < 8; ++kt) {
            const int f0 = 32 * kt + 8 * q;
            short8 a;
            #pragma unroll
            for (int j = 0; j < 8; ++j) a[j] = (short)f2bf(fbrow[f0 + j]);
            afrag[kt] = a;
        }
    }
    // fb[:,256] for the scalar fixup: rows 16w + 4q + r  (matches D layout)
    float fb256[4];
    #pragma unroll
    for (int r = 0; r < 4; ++r) fb256[r] = fb[(16 * w + 4 * q + r) * F_ + 256];

    // ---- init_min over first 20 frames (exact, like reference) ----
    const int f_own = tid;
    float mn = 1e30f;
    #pragma unroll
    for (int t = 0; t < 20; ++t) mn = fminf(mn, magp[(size_t)f_own * T_ + t]);
    const float initv  = fmaxf(mn, 1e-5f);
    const float floorv = 0.5f * initv;
    float nf = initv;

    float nf256 = 0.f, floor256 = 0.f;
    if (tid == 0) {
        float m2 = 1e30f;
        for (int t = 0; t < 20; ++t) m2 = fminf(m2, magp[(size_t)256 * T_ + t]);
        float iv = fmaxf(m2, 1e-5f);
        nf256 = iv; floor256 = 0.5f * iv;
    }

    const int bodyBeg = TPC * c;
    const int tileBeg = (c == 0) ? 0 : bodyBeg - WTILES;
    const int tileEnd = min(bodyBeg + TPC, NTILES);

    for (int tile = tileBeg; tile < tileEnd; ++tile) {
        const bool body = (tile >= bodyBeg);
        const int t0 = tile * TT_;

        __syncthreads();   // protect tile16 from previous einsum readers
        // ---- stage mag tile: wave w takes rows f = 4r + w (coalesced 256B rows) ----
        #pragma unroll 8
        for (int r = 0; r < 64; ++r) {
            const int f = 4 * r + w;
            const float g = magp[(size_t)f * T_ + (t0 + lane)];
            tile16[lane * 256 + (f ^ ((lane & 15) << 3))] = f2bf(g);
        }
        if (w == 0) mag256s[lane] = magp[(size_t)256 * T_ + (t0 + lane)];
        __syncthreads();

        // ---- sequential scan (thread owns f = tid), vnr written in place ----
        {
            float nfl = nf;
            if (body) {
                #pragma unroll 4
                for (int j = 0; j < 64; ++j) {
                    const int idx = j * 256 + (f_own ^ ((j & 15) << 3));
                    const float x = bf2f(tile16[idx]);
                    const float a = (x > nfl) ? rise : fall;
                    nfl = fmaxf(nfl + a * (x - nfl), floorv);
                    const float vnr = x * __builtin_amdgcn_rcpf(ns * nfl + 1e-8f);
                    tile16[idx] = f2bf(vnr);
                }
            } else {
                #pragma unroll 4
                for (int j = 0; j < 64; ++j) {
                    const float x = bf2f(tile16[j * 256 + (f_own ^ ((j & 15) << 3))]);
                    const float a = (x > nfl) ? rise : fall;
                    nfl = fmaxf(nfl + a * (x - nfl), floorv);
                }
            }
            nf = nfl;
            if (tid == 0) {   // f = 256 sequence (fp32 column)
                float nl = nf256;
                for (int j = 0; j < 64; ++j) {
                    const float x = mag256s[j];
                    const float a = (x > nl) ? rise : fall;
                    nl = fmaxf(nl + a * (x - nl), floor256);
                    if (body) vnr256s[j] = x * __builtin_amdgcn_rcpf(ns * nl + 1e-8f);
                }
                nf256 = nl;
            }
        }
        if (!body) continue;
        __syncthreads();

        // ---- einsum: out[n,t] = tanh(0.1 * sum_f fb[n,f]*vnr[f,t]) via MFMA ----
        floatx4 acc[4];
        #pragma unroll
        for (int tt = 0; tt < 4; ++tt) acc[tt] = (floatx4){0.f, 0.f, 0.f, 0.f};

        #pragma unroll
        for (int kt = 0; kt < 8; ++kt) {
            #pragma unroll
            for (int tt = 0; tt < 4; ++tt) {
                const int t = tt * 16 + l15;
                const short8* bp = (const short8*)
                    &tile16[t * 256 + ((32 * kt + 8 * q) ^ (l15 << 3))];
                acc[tt] = __builtin_amdgcn_mfma_f32_16x16x32_bf16(afrag[kt], *bp, acc[tt], 0, 0, 0);
            }
        }

        const size_t outb = (size_t)b * NB_ * T_;
        #pragma unroll
        for (int tt = 0; tt < 4; ++tt) {
            const int t = tt * 16 + l15;
            const float v256 = vnr256s[t];
            #pragma unroll
            for (int r = 0; r < 4; ++r) {
                const float s = acc[tt][r] + fb256[r] * v256;        // s >= 0
                const float e = __expf(s * 0.2f);                    // e^(2*s/10)
                const float y = 1.0f - 2.0f * __builtin_amdgcn_rcpf(e + 1.0f);  // tanh(s/10)
                out[outb + (size_t)(16 * w + 4 * q + r) * T_ + (size_t)(t0 + t)] = y;
            }
        }
    }
}

extern "C" void kernel_launch(void* const* d_in, const int* in_sizes, int n_in,
                              void* d_out, int out_size, void* d_ws, size_t ws_size,
                              hipStream_t stream) {
    (void)in_sizes; (void)n_in; (void)d_ws; (void)ws_size; (void)out_size;
    const float* mag = (const float*)d_in[0];
    const float* fb  = (const float*)d_in[1];
    const float* ns  = (const float*)d_in[2];
    const float* rr  = (const float*)d_in[3];
    const float* rf  = (const float*)d_in[4];
    float* out = (float*)d_out;

    dim3 grid(B_ * NCHUNK);   // 512 blocks = 16 b x 32 chunks
    dim3 block(256);
    hipLaunchKernelGGL(vnr_fused_kernel, grid, block, 0, stream, mag, fb, ns, rr, rf, out);
}